// Round 1
// baseline (561.367 us; speedup 1.0000x reference)
//
#include <hip/hip_runtime.h>

// CRF NLL: forward log-partition (sequential scan over S) + gold score.
// B,S,T fixed by the problem.
#define BB 512
#define SS 512
#define TT 64
#define START_TAG 62
#define STOP_TAG 63

#define LOG2E 1.4426950408889634f
#define LN2   0.6931471805599453f

__device__ __forceinline__ float bcastf(float x, int lane) {
    return __int_as_float(__builtin_amdgcn_readlane(__float_as_int(x), lane));
}

// ---------------- forward (log partition) ----------------
// 1 block (128 thr = 2 waves) per batch. lane = 'to' tag. Each wave reduces
// over 32 'from' values; partials combined through double-buffered LDS with
// one barrier per step. Both waves hold the full partition vector redundantly
// (identical fp ops -> identical values), so per-'from' broadcasts are plain
// v_readlane within each wave.
__global__ __launch_bounds__(128) void crf_forward(
    const float* __restrict__ feats, const int* __restrict__ mask,
    const float* __restrict__ trans, float* __restrict__ out)
{
    const int b    = blockIdx.x;
    const int tid  = threadIdx.x;
    const int lane = tid & 63;
    const int w    = tid >> 6;          // wave id: 0 or 1

    __shared__ float pbuf[2][128];
    __shared__ int   lcnt[2];

    // ---- sequence length from prefix-contiguous mask ----
    int cnt = 0;
    const int* mrow = mask + b * SS;
    #pragma unroll
    for (int s = tid; s < SS; s += 128) cnt += (mrow[s] != 0);
    #pragma unroll
    for (int off = 32; off; off >>= 1) cnt += __shfl_xor(cnt, off);
    if (lane == 0) lcnt[w] = cnt;
    __syncthreads();
    const int len = lcnt[0] + lcnt[1];

    // ---- preload this wave's transition half-column, scaled to log2 space ----
    // vt[i] = trans[from = w*32+i][to = lane] * log2(e)
    float vt[32];
    #pragma unroll
    for (int i = 0; i < 32; ++i)
        vt[i] = trans[(w * 32 + i) * TT + lane] * LOG2E;

    const float* frow = feats + (size_t)b * SS * TT;

    // ---- init: P[to] = feats[b,0,to] + trans[START,to] ----
    float P = frow[lane] + trans[START_TAG * TT + lane];

    float f_cur = frow[TT + lane];      // feats row for s=1 (len >= 2 always here)

    for (int s = 1; s < len; ++s) {
        // prefetch next feats row early so the barrier's vmcnt drain is cheap
        float f_next = f_cur;
        if (s + 1 < SS) f_next = frow[(size_t)(s + 1) * TT + lane];

        // wave-uniform offset (any offset is exact for lse; lane0's P is
        // within ~10 of the max so exp2 args stay small)
        const float offs = bcastf(P, 0);
        const float pl   = (P - offs) * LOG2E;   // lane = 'from' index for broadcast

        float a0 = 0.f, a1 = 0.f, a2 = 0.f, a3 = 0.f;
        #pragma unroll
        for (int i = 0; i < 32; i += 4) {
            const int fbase = w * 32 + i;
            float s0 = bcastf(pl, fbase + 0);
            float s1 = bcastf(pl, fbase + 1);
            float s2 = bcastf(pl, fbase + 2);
            float s3 = bcastf(pl, fbase + 3);
            a0 += __builtin_amdgcn_exp2f(s0 + vt[i + 0]);
            a1 += __builtin_amdgcn_exp2f(s1 + vt[i + 1]);
            a2 += __builtin_amdgcn_exp2f(s2 + vt[i + 2]);
            a3 += __builtin_amdgcn_exp2f(s3 + vt[i + 3]);
        }
        const float partial = (a0 + a1) + (a2 + a3);

        pbuf[s & 1][tid] = partial;
        __syncthreads();
        const float total = partial + pbuf[s & 1][tid ^ 64];

        P = f_cur + offs + LN2 * __builtin_amdgcn_logf(total);
        f_cur = f_next;
    }

    // ---- final transition to STOP: lse_from(P[from] + trans[from,STOP]) ----
    const float offs = bcastf(P, 0);
    const float pl   = (P - offs) * LOG2E;                 // lane = 'from'
    const float ts   = trans[lane * TT + STOP_TAG] * LOG2E;
    float e = __builtin_amdgcn_exp2f(pl + ts);
    #pragma unroll
    for (int off = 32; off; off >>= 1) e += __shfl_xor(e, off);

    if (tid == 0)
        atomicAdd(out, offs + LN2 * __builtin_amdgcn_logf(e));
}

// ---------------- gold score ----------------
// 1 wave per batch; lanes stride over s.
__global__ __launch_bounds__(64) void crf_gold(
    const float* __restrict__ feats, const int* __restrict__ mask,
    const int* __restrict__ tags, const float* __restrict__ trans,
    float* __restrict__ out)
{
    const int b    = blockIdx.x;
    const int lane = threadIdx.x;

    const int*   mrow = mask + b * SS;
    const int*   trow = tags + b * SS;
    const float* frow = feats + (size_t)b * SS * TT;

    int   cnt = 0;
    float acc = 0.f;
    for (int s = lane; s < SS; s += 64) {
        if (mrow[s] != 0) {
            ++cnt;
            const int tag  = trow[s];
            const int prev = (s == 0) ? START_TAG : trow[s - 1];
            acc += frow[(size_t)s * TT + tag] + trans[prev * TT + tag];
        }
    }
    #pragma unroll
    for (int off = 32; off; off >>= 1) {
        acc += __shfl_xor(acc, off);
        cnt += __shfl_xor(cnt, off);
    }
    if (lane == 0) {
        const int end_id = trow[cnt - 1];
        atomicAdd(out, -(acc + trans[end_id * TT + STOP_TAG]));
    }
}

__global__ void zero_out(float* out) { out[0] = 0.f; }

extern "C" void kernel_launch(void* const* d_in, const int* in_sizes, int n_in,
                              void* d_out, int out_size, void* d_ws, size_t ws_size,
                              hipStream_t stream) {
    const float* feats = (const float*)d_in[0];   // (B,S,T) f32
    const int*   mask  = (const int*)d_in[1];     // (B,S)   int (0/1)
    const int*   tags  = (const int*)d_in[2];     // (B,S)   int
    const float* trans = (const float*)d_in[3];   // (T,T)   f32
    float* out = (float*)d_out;

    zero_out<<<1, 1, 0, stream>>>(out);
    crf_forward<<<BB, 128, 0, stream>>>(feats, mask, trans, out);
    crf_gold<<<BB, 64, 0, stream>>>(feats, mask, tags, trans, out);
}

// Round 2
// 262.031 us; speedup vs baseline: 2.1424x; 2.1424x over previous
//
#include <hip/hip_runtime.h>

// CRF NLL, round 2: forward recursion kept in exp-space.
//   E[to] <- exp2(f*log2e) * ldexp( sum_from E[from]*M[from,to], -k )
// with M = exp(trans) precomputed in 64 VGPRs per lane, and k an exact
// power-of-2 rebase whose running sum is folded back at the end.
// One wave per batch (no barriers, no LDS, no per-step log). Wave 1 of each
// block computes the gold score for the same batch concurrently.
#define BB 512
#define SS 512
#define TT 64
#define START_TAG 62
#define STOP_TAG 63

#define LOG2E 1.4426950408889634f
#define LN2   0.6931471805599453f

__device__ __forceinline__ float bcast0(float x) {
    return __int_as_float(__builtin_amdgcn_readfirstlane(__float_as_int(x)));
}
__device__ __forceinline__ float rlane(float x, int l) {
    return __int_as_float(__builtin_amdgcn_readlane(__float_as_int(x), l));
}

__global__ __launch_bounds__(128) void crf_main(
    const float* __restrict__ feats, const int* __restrict__ mask,
    const int* __restrict__ tags, const float* __restrict__ trans,
    float* __restrict__ out)
{
    const int b    = blockIdx.x;
    const int tid  = threadIdx.x;
    const int lane = tid & 63;

    const float* frow = feats + (size_t)b * SS * TT;
    const int*   mrow = mask + b * SS;

    if (tid < 64) {
        // ---------------- forward (log partition), one wave per batch --------
        int cnt = 0;
        #pragma unroll
        for (int s = lane; s < SS; s += 64) cnt += (mrow[s] != 0);
        #pragma unroll
        for (int off = 32; off; off >>= 1) cnt += __shfl_xor(cnt, off);
        const int len = cnt;

        // M[from=i][to=lane] in exp2 space (constant across the scan)
        float vt[64];
        #pragma unroll
        for (int i = 0; i < 64; ++i)
            vt[i] = __builtin_amdgcn_exp2f(trans[i * TT + lane] * LOG2E);

        // init: P0[to] = f[0,to] + trans[START,to];  E = exp2((P0-offs)*log2e)
        const float P0   = frow[lane] + trans[START_TAG * TT + lane];
        const float offs = bcast0(P0);
        float E = __builtin_amdgcn_exp2f((P0 - offs) * LOG2E);
        int ksum = 0;

        float f_cur = frow[TT + lane];            // feats row s=1 (len >= 2)
        for (int s = 1; s < len; ++s) {
            float f_next = f_cur;
            if (s + 1 < SS) f_next = frow[(size_t)(s + 1) * TT + lane];

            // fe depends only on f_cur -> issues ahead of the fma stream
            const float fe = __builtin_amdgcn_exp2f(f_cur * LOG2E);

            float a0 = 0.f, a1 = 0.f, a2 = 0.f, a3 = 0.f;
            #pragma unroll
            for (int i = 0; i < 64; i += 4) {
                const float e0 = rlane(E, i + 0);
                const float e1 = rlane(E, i + 1);
                const float e2 = rlane(E, i + 2);
                const float e3 = rlane(E, i + 3);
                a0 = fmaf(e0, vt[i + 0], a0);
                a1 = fmaf(e1, vt[i + 1], a1);
                a2 = fmaf(e2, vt[i + 2], a2);
                a3 = fmaf(e3, vt[i + 3], a3);
            }
            const float D = (a0 + a1) + (a2 + a3);

            // exact power-of-2 rebase: k = floor exponent of D at lane 0
            const int k = ((__builtin_amdgcn_readfirstlane(__float_as_int(D))
                            >> 23) & 0xff) - 127;
            ksum += k;
            E = fe * ldexpf(D, -k);
            f_cur = f_next;
        }

        // final transition to STOP: lse_from(P[from] + trans[from,STOP])
        const float ts = __builtin_amdgcn_exp2f(trans[lane * TT + STOP_TAG] * LOG2E);
        float e = E * ts;
        #pragma unroll
        for (int off = 32; off; off >>= 1) e += __shfl_xor(e, off);

        if (lane == 0)
            atomicAdd(out, offs + (float)ksum * LN2
                           + LN2 * __builtin_amdgcn_logf(e));
    } else {
        // ---------------- gold score, wave 1 of the block --------------------
        const int* trow = tags + b * SS;
        int   cnt = 0;
        float acc = 0.f;
        for (int s = lane; s < SS; s += 64) {
            if (mrow[s] != 0) {
                ++cnt;
                const int tag  = trow[s];
                const int prev = (s == 0) ? START_TAG : trow[s - 1];
                acc += frow[(size_t)s * TT + tag] + trans[prev * TT + tag];
            }
        }
        #pragma unroll
        for (int off = 32; off; off >>= 1) {
            acc += __shfl_xor(acc, off);
            cnt += __shfl_xor(cnt, off);
        }
        if (lane == 0) {
            const int end_id = trow[cnt - 1];
            atomicAdd(out, -(acc + trans[end_id * TT + STOP_TAG]));
        }
    }
}

__global__ void zero_out(float* out) { out[0] = 0.f; }

extern "C" void kernel_launch(void* const* d_in, const int* in_sizes, int n_in,
                              void* d_out, int out_size, void* d_ws, size_t ws_size,
                              hipStream_t stream) {
    const float* feats = (const float*)d_in[0];   // (B,S,T) f32
    const int*   mask  = (const int*)d_in[1];     // (B,S)   int (0/1)
    const int*   tags  = (const int*)d_in[2];     // (B,S)   int
    const float* trans = (const float*)d_in[3];   // (T,T)   f32
    float* out = (float*)d_out;

    zero_out<<<1, 1, 0, stream>>>(out);
    crf_main<<<BB, 128, 0, stream>>>(feats, mask, tags, trans, out);
}